// Round 5
// baseline (302.549 us; speedup 1.0000x reference)
//
#include <hip/hip_runtime.h>
#include <math.h>

#define NN 50000
#define NE 800000
#define F_IN 512
#define F_MID 256
#define F_OUT 40
#define LN_EPS 1e-5f

typedef float f32x4 __attribute__((ext_vector_type(4)));
typedef short s16x8 __attribute__((ext_vector_type(8)));
typedef unsigned short ushort;

__device__ __forceinline__ short f2bf(float f) {
    unsigned u = __float_as_uint(f);
    return (short)((u + 0x7FFF + ((u >> 16) & 1)) >> 16);  // RNE
}
__device__ __forceinline__ float bf2f(ushort u) {
    return __uint_as_float(((unsigned)u) << 16);
}

// ---------------- degree count (int) ----------------
__global__ void k_count(const int* __restrict__ ei, int* __restrict__ cnt) {
    int e = blockIdx.x * blockDim.x + threadIdx.x;
    if (e < NE) atomicAdd(&cnt[ei[NE + e]], 1);
}

// ---------------- hierarchical scan (+ dinv fused) ----------------
__global__ __launch_bounds__(1024) void k_scan1(const int* __restrict__ cnt,
                                                int* __restrict__ rs,
                                                int* __restrict__ bsum,
                                                float* __restrict__ dinv) {
    __shared__ int wsum[16];
    int t = threadIdx.x;
    int lane = t & 63, wid = t >> 6;
    int i = blockIdx.x * 1024 + t;
    int v = (i < NN) ? cnt[i] : 0;
    if (i < NN) dinv[i] = rsqrtf((float)(v + 1));  // +1 self loop
    int s = v;
#pragma unroll
    for (int o = 1; o < 64; o <<= 1) {
        int u = __shfl_up(s, o, 64);
        if (lane >= o) s += u;
    }
    if (lane == 63) wsum[wid] = s;
    __syncthreads();
    if (wid == 0 && lane < 16) {
        int w = wsum[lane];
        int ss = w;
#pragma unroll
        for (int o = 1; o < 16; o <<= 1) {
            int u = __shfl_up(ss, o, 16);
            if (lane >= o) ss += u;
        }
        wsum[lane] = ss - w;
    }
    __syncthreads();
    int incl = s + wsum[wid];
    if (i < NN) rs[i + 1] = incl;
    if (t == 1023) bsum[blockIdx.x] = incl;
}

__global__ void k_scan2(int* __restrict__ bsum, int* __restrict__ boff, int nb) {
    int t = threadIdx.x;  // 64 threads
    int v = (t < nb) ? bsum[t] : 0;
    int s = v;
#pragma unroll
    for (int o = 1; o < 64; o <<= 1) {
        int u = __shfl_up(s, o, 64);
        if (t >= o) s += u;
    }
    if (t < nb) boff[t] = s - v;  // exclusive
}

__global__ __launch_bounds__(1024) void k_scan3(int* __restrict__ rs,
                                                const int* __restrict__ boff,
                                                int* __restrict__ cursor) {
    int i = blockIdx.x * 1024 + threadIdx.x;
    if (i == 0) { rs[0] = 0; cursor[0] = 0; }
    if (i < NN) {
        int v = rs[i + 1] + boff[blockIdx.x];
        rs[i + 1] = v;
        if (i + 1 < NN) cursor[i + 1] = v;
    }
}

// ---------------- fill CSR: esrc sorted by dst ----------------
__global__ void k_fill(const int* __restrict__ ei, int* __restrict__ cursor,
                       int* __restrict__ esrc) {
    int e = blockIdx.x * blockDim.x + threadIdx.x;
    if (e >= NE) return;
    int src = ei[e];
    int dst = ei[NE + e];
    int pos = atomicAdd(&cursor[dst], 1);
    esrc[pos] = src;
}

// ---------------- W1 [512][256] fp32 -> Wt [256][512] bf16 ----------------
__global__ void k_castW(const float* __restrict__ W, short* __restrict__ Wt) {
    int idx = blockIdx.x * 256 + threadIdx.x;
    int n = idx >> 9, k = idx & 511;
    Wt[idx] = f2bf(W[k * F_MID + n]);
}

// ---------------- W2 [256][40] fp32 -> W2t [48][256] bf16 (padded) ----------------
__global__ void k_castW2(const float* __restrict__ W, short* __restrict__ Wt) {
    int n = blockIdx.x;          // 0..47
    int k = threadIdx.x;         // 0..255
    Wt[n * 256 + k] = (n < F_OUT) ? f2bf(W[k * F_OUT + n]) : (short)0;
}

// ---------------- GEMM1 (MFMA bf16, dbuf BK=128): h1p = bf16((X@W1)*dinv) ----------------
// BM=64, BN=256, 4 waves. LDS 2x16KB double buffer; T14 stage split
// (issue next-chunk loads before MFMA phase, ds_write after).
__global__ __launch_bounds__(256) void k_gemm1m(const float* __restrict__ X,
                                                const short* __restrict__ Wt,
                                                const float* __restrict__ dinv,
                                                ushort* __restrict__ H) {
    __shared__ short As[2][64 * 128];  // 2 x 16 KB, 256B rows, swizzled
    int t = threadIdx.x;
    int r0 = blockIdx.x * 64;
    int r = t >> 2, q = t & 3;
    int gr = r0 + r;
    bool rowok = gr < NN;
    const float* xrow = X + (size_t)gr * F_IN;
    unsigned sw = (unsigned)((r & 7) << 4);
    char* lrow[2] = { (char*)&As[0][0] + r * 256, (char*)&As[1][0] + r * 256 };

    // ---- stage chunk 0 -> buf 0 ----
#pragma unroll
    for (int i = 0; i < 4; ++i) {
        float4 a = make_float4(0.f, 0.f, 0.f, 0.f);
        float4 b = make_float4(0.f, 0.f, 0.f, 0.f);
        if (rowok) {
            a = *(const float4*)&xrow[q * 32 + i * 8];
            b = *(const float4*)&xrow[q * 32 + i * 8 + 4];
        }
        s16x8 pk;
        pk[0] = f2bf(a.x); pk[1] = f2bf(a.y); pk[2] = f2bf(a.z); pk[3] = f2bf(a.w);
        pk[4] = f2bf(b.x); pk[5] = f2bf(b.y); pk[6] = f2bf(b.z); pk[7] = f2bf(b.w);
        *(s16x8*)(lrow[0] + (((unsigned)(q * 64 + i * 16)) ^ sw)) = pk;
    }
    __syncthreads();

    int wv = t >> 6, lane = t & 63;
    int n0 = wv * 64, lm = lane & 15, kg = lane >> 4;
    f32x4 acc[4][4];
#pragma unroll
    for (int m = 0; m < 4; ++m)
#pragma unroll
        for (int n = 0; n < 4; ++n) acc[m][n] = (f32x4){0.f, 0.f, 0.f, 0.f};

#pragma unroll
    for (int c = 0; c < 4; ++c) {
        int cur = c & 1;
        // issue next-chunk global loads early (hide under MFMA)
        float4 pa[4], pb[4];
        if (c < 3) {
#pragma unroll
            for (int i = 0; i < 4; ++i) {
                pa[i] = make_float4(0.f, 0.f, 0.f, 0.f);
                pb[i] = make_float4(0.f, 0.f, 0.f, 0.f);
                if (rowok) {
                    pa[i] = *(const float4*)&xrow[(c + 1) * 128 + q * 32 + i * 8];
                    pb[i] = *(const float4*)&xrow[(c + 1) * 128 + q * 32 + i * 8 + 4];
                }
            }
        }
        const char* Ab = (const char*)&As[cur][0];
#pragma unroll
        for (int ks = 0; ks < 4; ++ks) {
            s16x8 af[4], bfr[4];
#pragma unroll
            for (int m = 0; m < 4; ++m) {
                int rm = m * 16 + lm;
                unsigned off = (unsigned)(rm * 256) +
                               (((unsigned)(ks * 64 + kg * 16)) ^ ((unsigned)((rm & 7) << 4)));
                af[m] = *(const s16x8*)(Ab + off);
            }
#pragma unroll
            for (int n = 0; n < 4; ++n) {
                int rn = n0 + n * 16 + lm;
                bfr[n] = *(const s16x8*)&Wt[(size_t)rn * F_IN + c * 128 + ks * 32 + kg * 8];
            }
#pragma unroll
            for (int m = 0; m < 4; ++m)
#pragma unroll
                for (int n = 0; n < 4; ++n)
                    acc[m][n] = __builtin_amdgcn_mfma_f32_16x16x32_bf16(af[m], bfr[n], acc[m][n], 0, 0, 0);
        }
        if (c < 3) {
            char* lw = lrow[cur ^ 1];
#pragma unroll
            for (int i = 0; i < 4; ++i) {
                s16x8 pk;
                pk[0] = f2bf(pa[i].x); pk[1] = f2bf(pa[i].y);
                pk[2] = f2bf(pa[i].z); pk[3] = f2bf(pa[i].w);
                pk[4] = f2bf(pb[i].x); pk[5] = f2bf(pb[i].y);
                pk[6] = f2bf(pb[i].z); pk[7] = f2bf(pb[i].w);
                *(s16x8*)(lw + (((unsigned)(q * 64 + i * 16)) ^ sw)) = pk;
            }
            __syncthreads();
        }
    }

    // ---- epilogue: D row = m*16 + kg*4 + reg, col = n0 + n*16 + lm ----
#pragma unroll
    for (int m = 0; m < 4; ++m) {
#pragma unroll
        for (int reg = 0; reg < 4; ++reg) {
            int row = r0 + m * 16 + kg * 4 + reg;
            if (row < NN) {
                float s = dinv[row];
#pragma unroll
                for (int n = 0; n < 4; ++n) {
                    H[(size_t)row * F_MID + n0 + n * 16 + lm] = (ushort)f2bf(acc[m][n][reg] * s);
                }
            }
        }
    }
}

// ---------------- fused gather-agg + dinv + bias + LN(256) + ELU -> bf16 ----------------
__global__ __launch_bounds__(256) void k_agg1(const int* __restrict__ rs,
                                              const int* __restrict__ esrc,
                                              const ushort* __restrict__ H,
                                              const float* __restrict__ dinv,
                                              const float* __restrict__ b,
                                              const float* __restrict__ g,
                                              const float* __restrict__ be,
                                              ushort* __restrict__ O) {
    int node = blockIdx.x * 4 + (threadIdx.x >> 6);
    if (node >= NN) return;
    int lane = threadIdx.x & 63;
    int c = lane * 4;
    ushort4 sv = *(const ushort4*)&H[(size_t)node * F_MID + c];
    float a0 = bf2f(sv.x), a1 = bf2f(sv.y), a2 = bf2f(sv.z), a3 = bf2f(sv.w);
    int beg = rs[node], end = rs[node + 1];
    int j = beg;
    for (; j + 3 < end; j += 4) {
        int s0 = esrc[j], s1 = esrc[j + 1], s2 = esrc[j + 2], s3 = esrc[j + 3];
        ushort4 v0 = *(const ushort4*)&H[(size_t)s0 * F_MID + c];
        ushort4 v1 = *(const ushort4*)&H[(size_t)s1 * F_MID + c];
        ushort4 v2 = *(const ushort4*)&H[(size_t)s2 * F_MID + c];
        ushort4 v3 = *(const ushort4*)&H[(size_t)s3 * F_MID + c];
        a0 += bf2f(v0.x) + bf2f(v1.x) + bf2f(v2.x) + bf2f(v3.x);
        a1 += bf2f(v0.y) + bf2f(v1.y) + bf2f(v2.y) + bf2f(v3.y);
        a2 += bf2f(v0.z) + bf2f(v1.z) + bf2f(v2.z) + bf2f(v3.z);
        a3 += bf2f(v0.w) + bf2f(v1.w) + bf2f(v2.w) + bf2f(v3.w);
    }
    for (; j < end; ++j) {
        int s0 = esrc[j];
        ushort4 v0 = *(const ushort4*)&H[(size_t)s0 * F_MID + c];
        a0 += bf2f(v0.x); a1 += bf2f(v0.y); a2 += bf2f(v0.z); a3 += bf2f(v0.w);
    }
    float s = dinv[node];
    float v0 = s * a0 + b[c + 0];
    float v1 = s * a1 + b[c + 1];
    float v2 = s * a2 + b[c + 2];
    float v3 = s * a3 + b[c + 3];
    float sum = v0 + v1 + v2 + v3;
    float sq = v0 * v0 + v1 * v1 + v2 * v2 + v3 * v3;
#pragma unroll
    for (int o = 32; o; o >>= 1) {
        sum += __shfl_xor(sum, o, 64);
        sq  += __shfl_xor(sq, o, 64);
    }
    float mu = sum * (1.0f / F_MID);
    float var = sq * (1.0f / F_MID) - mu * mu;
    float rstd = rsqrtf(var + LN_EPS);
    float y0 = (v0 - mu) * rstd * g[c + 0] + be[c + 0];
    float y1 = (v1 - mu) * rstd * g[c + 1] + be[c + 1];
    float y2 = (v2 - mu) * rstd * g[c + 2] + be[c + 2];
    float y3 = (v3 - mu) * rstd * g[c + 3] + be[c + 3];
    ushort4 o4;
    o4.x = (ushort)f2bf(y0 > 0.f ? y0 : expm1f(y0));
    o4.y = (ushort)f2bf(y1 > 0.f ? y1 : expm1f(y1));
    o4.z = (ushort)f2bf(y2 > 0.f ? y2 : expm1f(y2));
    o4.w = (ushort)f2bf(y3 > 0.f ? y3 : expm1f(y3));
    *(ushort4*)&O[(size_t)node * F_MID + c] = o4;
}

// ---------------- GEMM2 (MFMA bf16): h2p = bf16((h1 @ W2) * dinv) [NN,40] ----------------
__global__ __launch_bounds__(256) void k_gemm2m(const ushort* __restrict__ Hin,
                                                const short* __restrict__ W2t,
                                                const float* __restrict__ dinv,
                                                ushort* __restrict__ H2) {
    __shared__ short As[64 * 256];  // 32 KB, swizzled (512B rows)
    int t = threadIdx.x;
    int r0 = blockIdx.x * 64;

    {
        int r = t >> 2;
        int q = t & 3;
        int gr = r0 + r;
        char* lrow = (char*)As + r * 512;
        unsigned sw = (unsigned)((r & 7) << 4);
#pragma unroll
        for (int j = 0; j < 8; ++j) {
            int chunk = q + j * 4;  // 0..31, 16B each
            s16x8 p = (s16x8)0;
            if (gr < NN) p = *(const s16x8*)&Hin[(size_t)gr * F_MID + chunk * 8];
            *(s16x8*)(lrow + (((unsigned)(chunk * 16)) ^ sw)) = p;
        }
    }
    __syncthreads();

    int wv = t >> 6;
    int lane = t & 63;
    int lm = lane & 15;
    int kg = lane >> 4;
    f32x4 acc[3];
#pragma unroll
    for (int n = 0; n < 3; ++n) acc[n] = (f32x4){0.f, 0.f, 0.f, 0.f};

#pragma unroll
    for (int ks = 0; ks < 8; ++ks) {
        int rm = wv * 16 + lm;
        unsigned byteoff = (unsigned)(rm * 512) +
                           (((unsigned)(ks * 64 + kg * 16)) ^ ((unsigned)((rm & 7) << 4)));
        s16x8 af = *(const s16x8*)((const char*)As + byteoff);
#pragma unroll
        for (int n = 0; n < 3; ++n) {
            int rn = n * 16 + lm;
            s16x8 bfr = *(const s16x8*)&W2t[rn * F_MID + ks * 32 + kg * 8];
            acc[n] = __builtin_amdgcn_mfma_f32_16x16x32_bf16(af, bfr, acc[n], 0, 0, 0);
        }
    }

#pragma unroll
    for (int n = 0; n < 3; ++n) {
        int col = n * 16 + lm;
        if (col >= F_OUT) continue;
#pragma unroll
        for (int reg = 0; reg < 4; ++reg) {
            int row = r0 + wv * 16 + kg * 4 + reg;
            if (row < NN) {
                H2[(size_t)row * F_OUT + col] = (ushort)f2bf(acc[n][reg] * dinv[row]);
            }
        }
    }
}

// ------- fused gather-agg2 + dinv + bias + LN(40) + ELU + log_softmax -------
__global__ __launch_bounds__(256) void k_agg2(const int* __restrict__ rs,
                                              const int* __restrict__ esrc,
                                              const ushort* __restrict__ H2,
                                              const float* __restrict__ dinv,
                                              const float* __restrict__ b,
                                              const float* __restrict__ g,
                                              const float* __restrict__ be,
                                              float* __restrict__ out) {
    int node = blockIdx.x * 4 + (threadIdx.x >> 6);
    if (node >= NN) return;
    int lane = threadIdx.x & 63;
    bool act = lane < F_OUT;
    size_t off = (size_t)node * F_OUT + lane;
    float acc = act ? bf2f(H2[off]) : 0.f;
    int beg = rs[node], end = rs[node + 1];
    int j = beg;
    for (; j + 1 < end; j += 2) {
        int s0 = esrc[j], s1 = esrc[j + 1];
        if (act) {
            acc += bf2f(H2[(size_t)s0 * F_OUT + lane]);
            acc += bf2f(H2[(size_t)s1 * F_OUT + lane]);
        }
    }
    if (j < end) {
        int s0 = esrc[j];
        if (act) acc += bf2f(H2[(size_t)s0 * F_OUT + lane]);
    }
    float v = act ? dinv[node] * acc + b[lane] : 0.f;
    float sum = v;
    float sq = v * v;
#pragma unroll
    for (int o = 32; o; o >>= 1) {
        sum += __shfl_xor(sum, o, 64);
        sq  += __shfl_xor(sq, o, 64);
    }
    float mu = sum * (1.0f / F_OUT);
    float var = sq * (1.0f / F_OUT) - mu * mu;
    float rstd = rsqrtf(var + LN_EPS);
    float y = act ? ((v - mu) * rstd * g[lane] + be[lane]) : 0.f;
    float el = y > 0.f ? y : expm1f(y);
    float m = act ? el : -INFINITY;
#pragma unroll
    for (int o = 32; o; o >>= 1) m = fmaxf(m, __shfl_xor(m, o, 64));
    float ex = act ? expf(el - m) : 0.f;
    float se = ex;
#pragma unroll
    for (int o = 32; o; o >>= 1) se += __shfl_xor(se, o, 64);
    if (act) out[off] = el - m - logf(se);
}

extern "C" void kernel_launch(void* const* d_in, const int* in_sizes, int n_in,
                              void* d_out, int out_size, void* d_ws, size_t ws_size,
                              hipStream_t stream) {
    const float* x   = (const float*)d_in[0];
    const int*   ei  = (const int*)d_in[1];
    const float* W1  = (const float*)d_in[2];
    const float* b1  = (const float*)d_in[3];
    const float* g1  = (const float*)d_in[4];
    const float* be1 = (const float*)d_in[5];
    const float* W2  = (const float*)d_in[6];
    const float* b2  = (const float*)d_in[7];
    const float* g2  = (const float*)d_in[8];
    const float* be2 = (const float*)d_in[9];
    float* out = (float*)d_out;

    char* p = (char*)d_ws;
    float* dinv = (float*)p;            p += 50000 * 4;
    ushort* h1p = (ushort*)p;           p += (size_t)NN * F_MID * 2;
    ushort* h1  = (ushort*)p;           p += (size_t)NN * F_MID * 2;
    ushort* h2p = (ushort*)p;           p += (size_t)NN * F_OUT * 2;
    short* Wt   = (short*)p;            p += (size_t)F_MID * F_IN * 2;
    short* W2t  = (short*)p;            p += 48 * 256 * 2;
    int* cnt      = (int*)p;            p += NN * 4;
    int* rowstart = (int*)p;            p += (NN + 1) * 4;
    int* cursor   = (int*)p;            p += NN * 4;
    int* bsum     = (int*)p;            p += 64 * 4;
    int* boff     = (int*)p;            p += 64 * 4;
    int* esrc     = (int*)p;

    const int NB = (NN + 1023) / 1024;  // 49

    hipMemsetAsync(cnt, 0, NN * sizeof(int), stream);
    k_count<<<(NE + 255) / 256, 256, 0, stream>>>(ei, cnt);
    k_scan1<<<NB, 1024, 0, stream>>>(cnt, rowstart, bsum, dinv);
    k_scan2<<<1, 64, 0, stream>>>(bsum, boff, NB);
    k_scan3<<<NB, 1024, 0, stream>>>(rowstart, boff, cursor);
    k_fill<<<(NE + 255) / 256, 256, 0, stream>>>(ei, cursor, esrc);
    k_castW<<<512, 256, 0, stream>>>(W1, Wt);
    k_castW2<<<48, 256, 0, stream>>>(W2, W2t);

    k_gemm1m<<<(NN + 63) / 64, 256, 0, stream>>>(x, Wt, dinv, h1p);
    k_agg1<<<(NN + 3) / 4, 256, 0, stream>>>(rowstart, esrc, h1p, dinv, b1, g1, be1, h1);
    k_gemm2m<<<(NN + 63) / 64, 256, 0, stream>>>(h1, W2t, dinv, h2p);
    k_agg2<<<(NN + 3) / 4, 256, 0, stream>>>(rowstart, esrc, h2p, dinv, b2, g2, be2, out);
}